// Round 7
// baseline (1575.560 us; speedup 1.0000x reference)
//
#include <hip/hip_runtime.h>

#define NN 100000
#define NE 1600000
#define EPS_BN 1e-5f

typedef unsigned short ushort_t;
typedef unsigned long long u64;
typedef short v8s __attribute__((ext_vector_type(8)));     // 8 bf16 (4 VGPR)
typedef float v4f __attribute__((ext_vector_type(4)));     // 4 fp32 acc
typedef float nt_f4 __attribute__((ext_vector_type(4)));   // native vec for nontemporal builtins
typedef ushort_t nt_u2 __attribute__((ext_vector_type(2)));

__device__ __forceinline__ float lk(float x){ return x >= 0.f ? x : 0.1f*x; }

__device__ __forceinline__ ushort_t f2bf(float x){
  unsigned u = __float_as_uint(x);
  unsigned r = (u + 0x7fffu + ((u >> 16) & 1u)) >> 16;
  return (ushort_t)r;
}
__device__ __forceinline__ float bf2f(ushort_t h){
  return __uint_as_float(((unsigned)h) << 16);
}
__device__ __forceinline__ void split2(float x, ushort_t& hi, ushort_t& lo){
  hi = f2bf(x);
  lo = f2bf(x - bf2f(hi));
}

// async 16B global->LDS (lds dst is wave-uniform base; HW adds lane*16)
__device__ __forceinline__ void gload16(const ushort_t* g, ushort_t* l){
  __builtin_amdgcn_global_load_lds((const __attribute__((address_space(1))) void*)g,
                                   (__attribute__((address_space(3))) void*)l, 16, 0, 0);
}

// ---------------- degree+count histogram: ONE packed u64 atomic per edge ----------------
__global__ void zero_acc(u64* __restrict__ acc, int n){
  int i = blockIdx.x*256 + threadIdx.x;
  if (i < n) acc[i] = 0ull;
}

__global__ void edge_hist(const int* __restrict__ dst, const float* __restrict__ ew,
                          u64* __restrict__ acc, int e){
  int i = blockIdx.x*256 + threadIdx.x;
  if (i < e){
    int d = dst[i];
    unsigned fx = (unsigned)(ew[i] * 67108864.0f + 0.5f);   // 2^26 fixed point
    atomicAdd(&acc[d], (1ull << 40) | (u64)fx);
  }
}

__global__ void finalize_acc(const u64* __restrict__ acc, float* __restrict__ dinv,
                             int* __restrict__ cnt, int n){
  int i = blockIdx.x*256 + threadIdx.x;
  if (i < n){
    u64 v = acc[i];
    cnt[i] = (int)(v >> 40);
    double w = (double)(v & 0xFFFFFFFFFFull) * (1.0/67108864.0);
    dinv[i] = rsqrtf((float)(1.0 + w));   // +1 self loop
  }
}

// ---------------- exclusive scan (3-kernel) ----------------
__global__ __launch_bounds__(1024) void scan_block(const int* __restrict__ in, int* __restrict__ out,
                                                   int* __restrict__ bsum, int n){
  __shared__ int s[1024];
  int t = threadIdx.x;
  int i = blockIdx.x*1024 + t;
  int v = (i < n) ? in[i] : 0;
  s[t] = v; __syncthreads();
  for (int off = 1; off < 1024; off <<= 1){
    int x = (t >= off) ? s[t-off] : 0;
    __syncthreads();
    s[t] += x;
    __syncthreads();
  }
  if (i < n) out[i] = s[t] - v;
  if (t == 1023) bsum[blockIdx.x] = s[1023];
}

__global__ void scan_small(int* __restrict__ bsum, int nb){
  __shared__ int s[128];
  int t = threadIdx.x;
  int v = (t < nb) ? bsum[t] : 0;
  s[t] = v; __syncthreads();
  for (int off = 1; off < 128; off <<= 1){
    int x = (t >= off) ? s[t-off] : 0;
    __syncthreads();
    s[t] += x;
    __syncthreads();
  }
  if (t < nb) bsum[t] = s[t] - v;
}

__global__ __launch_bounds__(1024) void scan_add(int* __restrict__ rp, int* __restrict__ fill,
                                                 const int* __restrict__ bsum, int n, int etot){
  int i = blockIdx.x*1024 + threadIdx.x;
  if (i < n){
    int v = rp[i] + bsum[blockIdx.x];
    rp[i] = v;
    fill[i] = v;
  }
  if (i == 0) rp[n] = etot;
}

// ---------------- CSR fill: one scattered 8B store per edge ----------------
__global__ void fill_csr_k(const int* __restrict__ src, const int* __restrict__ dst,
                           const float* __restrict__ ew, const float* __restrict__ dinv,
                           int* __restrict__ fill, int2* __restrict__ csr_sw, int e){
  int i = blockIdx.x*256 + threadIdx.x;
  if (i >= e) return;
  int s = src[i], d = dst[i];
  int pos = atomicAdd(&fill[d], 1);
  float w = dinv[s] * ew[i] * dinv[d];
  csr_sw[pos] = make_int2(s, __float_as_int(w));
}

// ---------------- SpMM full-width (256 ch), gather by destination, fp32 ----------------
// Output stores are NON-TEMPORAL: the 100 MB out-stream must not evict the
// gather working set (the h array) from L3 — that eviction was the ~50% miss rate.
__global__ __launch_bounds__(256) void spmm_full(const float* __restrict__ h,
    const int* __restrict__ rp, const int2* __restrict__ csr_sw,
    const float* __restrict__ dinv, const float* __restrict__ bias,
    float* __restrict__ out, int n){
  int node = blockIdx.x*4 + (threadIdx.x >> 6);
  node = __builtin_amdgcn_readfirstlane(node);   // wave-uniform -> scalarize CSR loads
  if (node >= n) return;
  int lane = threadIdx.x & 63;
  const float* hb = h + lane*4;
  float di = dinv[node];
  float c0 = di * di;
  float4 hv = *(const float4*)(hb + (size_t)node*256);
  float4 bb = *(const float4*)(bias + lane*4);
  float ax = fmaf(c0, hv.x, bb.x);
  float ay = fmaf(c0, hv.y, bb.y);
  float az = fmaf(c0, hv.z, bb.z);
  float aw = fmaf(c0, hv.w, bb.w);
  int p = rp[node], pend = rp[node+1];
  for (; p + 4 <= pend; p += 4){
    int2 e0 = csr_sw[p],   e1 = csr_sw[p+1], e2 = csr_sw[p+2], e3 = csr_sw[p+3];
    float4 v0 = *(const float4*)(hb + (size_t)e0.x*256);
    float4 v1 = *(const float4*)(hb + (size_t)e1.x*256);
    float4 v2 = *(const float4*)(hb + (size_t)e2.x*256);
    float4 v3 = *(const float4*)(hb + (size_t)e3.x*256);
    float w0 = __int_as_float(e0.y), w1 = __int_as_float(e1.y);
    float w2 = __int_as_float(e2.y), w3 = __int_as_float(e3.y);
    ax = fmaf(w0, v0.x, ax); ay = fmaf(w0, v0.y, ay); az = fmaf(w0, v0.z, az); aw = fmaf(w0, v0.w, aw);
    ax = fmaf(w1, v1.x, ax); ay = fmaf(w1, v1.y, ay); az = fmaf(w1, v1.z, az); aw = fmaf(w1, v1.w, aw);
    ax = fmaf(w2, v2.x, ax); ay = fmaf(w2, v2.y, ay); az = fmaf(w2, v2.z, az); aw = fmaf(w2, v2.w, aw);
    ax = fmaf(w3, v3.x, ax); ay = fmaf(w3, v3.y, ay); az = fmaf(w3, v3.z, az); aw = fmaf(w3, v3.w, aw);
  }
  for (; p < pend; ++p){
    int2 e = csr_sw[p];
    float w = __int_as_float(e.y);
    float4 v = *(const float4*)(hb + (size_t)e.x*256);
    ax = fmaf(w, v.x, ax); ay = fmaf(w, v.y, ay); az = fmaf(w, v.z, az); aw = fmaf(w, v.w, aw);
  }
  nt_f4 r = (nt_f4){ax, ay, az, aw};
  __builtin_nontemporal_store(r, (nt_f4*)(out + (size_t)node*256 + lane*4));
}

// ---------------- conv1 SpMM: 128 ch over x, epilogue emits hi/lo bf16 split ----------------
__global__ __launch_bounds__(256) void spmm_x(const float* __restrict__ h,
    const int* __restrict__ rp, const int2* __restrict__ csr_sw,
    const float* __restrict__ dinv,
    ushort_t* __restrict__ ohi, ushort_t* __restrict__ olo, int n){
  int node = blockIdx.x*4 + (threadIdx.x >> 6);
  node = __builtin_amdgcn_readfirstlane(node);
  if (node >= n) return;
  int lane = threadIdx.x & 63;
  const float* hb = h + lane*2;
  float di = dinv[node];
  float c0 = di * di;
  float2 hv = *(const float2*)(hb + (size_t)node*128);
  float ax = c0 * hv.x;
  float ay = c0 * hv.y;
  int p = rp[node], pend = rp[node+1];
  for (; p + 8 <= pend; p += 8){
    int2 e0 = csr_sw[p],   e1 = csr_sw[p+1], e2 = csr_sw[p+2], e3 = csr_sw[p+3];
    int2 e4 = csr_sw[p+4], e5 = csr_sw[p+5], e6 = csr_sw[p+6], e7 = csr_sw[p+7];
    float2 v0 = *(const float2*)(hb + (size_t)e0.x*128);
    float2 v1 = *(const float2*)(hb + (size_t)e1.x*128);
    float2 v2 = *(const float2*)(hb + (size_t)e2.x*128);
    float2 v3 = *(const float2*)(hb + (size_t)e3.x*128);
    float2 v4 = *(const float2*)(hb + (size_t)e4.x*128);
    float2 v5 = *(const float2*)(hb + (size_t)e5.x*128);
    float2 v6 = *(const float2*)(hb + (size_t)e6.x*128);
    float2 v7 = *(const float2*)(hb + (size_t)e7.x*128);
    ax = fmaf(__int_as_float(e0.y), v0.x, ax); ay = fmaf(__int_as_float(e0.y), v0.y, ay);
    ax = fmaf(__int_as_float(e1.y), v1.x, ax); ay = fmaf(__int_as_float(e1.y), v1.y, ay);
    ax = fmaf(__int_as_float(e2.y), v2.x, ax); ay = fmaf(__int_as_float(e2.y), v2.y, ay);
    ax = fmaf(__int_as_float(e3.y), v3.x, ax); ay = fmaf(__int_as_float(e3.y), v3.y, ay);
    ax = fmaf(__int_as_float(e4.y), v4.x, ax); ay = fmaf(__int_as_float(e4.y), v4.y, ay);
    ax = fmaf(__int_as_float(e5.y), v5.x, ax); ay = fmaf(__int_as_float(e5.y), v5.y, ay);
    ax = fmaf(__int_as_float(e6.y), v6.x, ax); ay = fmaf(__int_as_float(e6.y), v6.y, ay);
    ax = fmaf(__int_as_float(e7.y), v7.x, ax); ay = fmaf(__int_as_float(e7.y), v7.y, ay);
  }
  for (; p < pend; ++p){
    int2 e = csr_sw[p];
    float w = __int_as_float(e.y);
    float2 v = *(const float2*)(hb + (size_t)e.x*128);
    ax = fmaf(w, v.x, ax); ay = fmaf(w, v.y, ay);
  }
  ushort_t hx, lx, hy, ly;
  split2(ax, hx, lx);
  split2(ay, hy, ly);
  size_t o = (size_t)node*128 + lane*2;
  nt_u2 hh = (nt_u2){hx, hy};
  nt_u2 ll = (nt_u2){lx, ly};
  __builtin_nontemporal_store(hh, (nt_u2*)(ohi + o));
  __builtin_nontemporal_store(ll, (nt_u2*)(olo + o));
}

// ---------------- BatchNorm ----------------
__global__ void zero_stats(float* __restrict__ stats){
  stats[threadIdx.x] = 0.f;   // 512 threads
}

__global__ __launch_bounds__(256) void bn_partial(const float* __restrict__ a,
                                                  float* __restrict__ stats, int n){
  int c = threadIdx.x;
  int r0 = blockIdx.x * 256;
  int rend = min(r0 + 256, n);
  float s = 0.f, s2 = 0.f;
  for (int r = r0; r < rend; ++r){
    float v = a[(size_t)r*256 + c];
    s += v;
    s2 = fmaf(v, v, s2);
  }
  atomicAdd(&stats[c], s);
  atomicAdd(&stats[256 + c], s2);
}

__global__ void bn_final(float* __restrict__ stats, const float* __restrict__ g,
                         const float* __restrict__ be, int n){
  int c = threadIdx.x;
  float inv_n = 1.0f / (float)n;
  float mean = stats[c] * inv_n;
  float var  = fmaxf(stats[256 + c] * inv_n - mean*mean, 0.f);
  float sc   = g[c] * rsqrtf(var + EPS_BN);
  stats[512 + c] = sc;
  stats[768 + c] = be[c] - mean * sc;
}

// bn scale/shift + leaky, emit hi/lo bf16 split directly (feeds next MFMA GEMM)
__global__ __launch_bounds__(256) void bn_apply_split(const float* __restrict__ a,
    const float* __restrict__ stats, ushort_t* __restrict__ hi, ushort_t* __restrict__ lo, int n){
  size_t i = (size_t)blockIdx.x*256 + threadIdx.x;   // one float4 per thread
  if (i >= (size_t)n*64) return;
  int c4 = (int)(i & 63);
  float4 v  = ((const float4*)a)[i];
  float4 sc = ((const float4*)(stats + 512))[c4];
  float4 sh = ((const float4*)(stats + 768))[c4];
  v.x = lk(fmaf(v.x, sc.x, sh.x));
  v.y = lk(fmaf(v.y, sc.y, sh.y));
  v.z = lk(fmaf(v.z, sc.z, sh.z));
  v.w = lk(fmaf(v.w, sc.w, sh.w));
  ushort4 h, l;
  split2(v.x, h.x, l.x); split2(v.y, h.y, l.y);
  split2(v.z, h.z, l.z); split2(v.w, h.w, l.w);
  ((ushort4*)hi)[i] = h;
  ((ushort4*)lo)[i] = l;
}

// W[K][M] fp32 -> transposed split WtHi/WtLo[M][K] bf16
__global__ void wsplit(const float* __restrict__ W, ushort_t* __restrict__ hiT,
                       ushort_t* __restrict__ loT, int K, int M){
  int i = blockIdx.x*256 + threadIdx.x;
  if (i >= K*M) return;
  int k = i / M, m = i % M;
  ushort_t h, l;
  split2(W[i], h, l);
  hiT[(size_t)m*K + k] = h;
  loT[(size_t)m*K + k] = l;
}

// ---------------- bf16x3 split MFMA GEMM ----------------
// C[n,M] = (Ahi+Alo)[n,K] @ (Bhi+Blo)^T  with B stored transposed [M][K].
// ACT: 0 none->Cf ; 1 bias+leaky ; 2 bias. SPLIT_OUT: write Chi/Clo instead of Cf.
template<int BM, int BN, int WM, int WN, int ACT, int SPLIT_OUT>
__global__ __launch_bounds__(256) void gemm_mfma(
    const ushort_t* __restrict__ Ahi_g, const ushort_t* __restrict__ Alo_g,
    const ushort_t* __restrict__ Bhi_g, const ushort_t* __restrict__ Blo_g,
    const float* __restrict__ bias,
    float* __restrict__ Cf, ushort_t* __restrict__ Chi, ushort_t* __restrict__ Clo,
    int nrows, int K, int M){
  constexpr int FI = WM/16, FJ = WN/16;
  constexpr int WCOLS = BN/WN;
  __shared__ ushort_t sAhi[BM*32];
  __shared__ ushort_t sAlo[BM*32];
  __shared__ ushort_t sBhi[BN*32];
  __shared__ ushort_t sBlo[BN*32];
  const int tid  = threadIdx.x;
  const int wave = tid >> 6;
  const int lane = tid & 63;
  const int r0 = blockIdx.x * BM;
  const int c0 = blockIdx.y * BN;
  const int wr0 = (wave / WCOLS) * WM;
  const int wc0 = (wave % WCOLS) * WN;
  const int m = lane & 15, q = lane >> 4;

  v4f acc[FI][FJ];
#pragma unroll
  for (int i = 0; i < FI; ++i)
#pragma unroll
    for (int j = 0; j < FJ; ++j) acc[i][j] = (v4f){0.f,0.f,0.f,0.f};

  const int srow = lane >> 2;                        // row within 16-row chunk
  const int kqlog = (lane & 3) ^ ((srow >> 1) & 3);  // swizzled logical 16B chunk
  const int fsw = (q ^ ((m >> 1) & 3)) * 8;          // frag read: swizzled k elem offset

  for (int kt = 0; kt < K; kt += 32){
#pragma unroll
    for (int c = 0; c < BM/64; ++c){                 // each wave stages BM/64 16-row A-chunks
      int cc = c*4 + wave;
      int gr = r0 + cc*16 + srow;
      gr = min(gr, nrows - 1);
      size_t go = (size_t)gr*K + kt + kqlog*8;
      gload16(Ahi_g + go, &sAhi[cc*512]);
      gload16(Alo_g + go, &sAlo[cc*512]);
    }
    for (int cc = wave; cc < BN/16; cc += 4){
      int gr = c0 + cc*16 + srow;
      size_t go = (size_t)gr*K + kt + kqlog*8;
      gload16(Bhi_g + go, &sBhi[cc*512]);
      gload16(Blo_g + go, &sBlo[cc*512]);
    }
    __syncthreads();   // drains vmcnt (global_load_lds) per barrier semantics

    v8s ah[FI], al[FI], bh[FJ], bl[FJ];
#pragma unroll
    for (int i = 0; i < FI; ++i){
      int off = (wr0 + i*16 + m)*32 + fsw;
      ah[i] = *(const v8s*)&sAhi[off];
      al[i] = *(const v8s*)&sAlo[off];
    }
#pragma unroll
    for (int j = 0; j < FJ; ++j){
      int off = (wc0 + j*16 + m)*32 + fsw;
      bh[j] = *(const v8s*)&sBhi[off];
      bl[j] = *(const v8s*)&sBlo[off];
    }
#pragma unroll
    for (int i = 0; i < FI; ++i)
#pragma unroll
      for (int j = 0; j < FJ; ++j){
        acc[i][j] = __builtin_amdgcn_mfma_f32_16x16x32_bf16(ah[i], bh[j], acc[i][j], 0, 0, 0);
        acc[i][j] = __builtin_amdgcn_mfma_f32_16x16x32_bf16(ah[i], bl[j], acc[i][j], 0, 0, 0);
        acc[i][j] = __builtin_amdgcn_mfma_f32_16x16x32_bf16(al[i], bh[j], acc[i][j], 0, 0, 0);
      }
    __syncthreads();
  }

  // epilogue: C/D layout col = lane&15, row = (lane>>4)*4 + reg  [m89/m91]
#pragma unroll
  for (int i = 0; i < FI; ++i){
#pragma unroll
    for (int j = 0; j < FJ; ++j){
      int col = c0 + wc0 + j*16 + m;
      float bv = (ACT >= 1) ? bias[col] : 0.f;
#pragma unroll
      for (int r = 0; r < 4; ++r){
        int row = r0 + wr0 + i*16 + q*4 + r;
        if (row >= nrows) continue;
        float v = acc[i][j][r] + bv;
        if (ACT == 1) v = lk(v);
        size_t o = (size_t)row*M + col;
        if (SPLIT_OUT){
          ushort_t h, l; split2(v, h, l);
          Chi[o] = h; Clo[o] = l;
        } else {
          Cf[o] = v;
        }
      }
    }
  }
}

// ---------------- launch ----------------
extern "C" void kernel_launch(void* const* d_in, const int* in_sizes, int n_in,
                              void* d_out, int out_size, void* d_ws, size_t ws_size,
                              hipStream_t stream){
  const float* x   = (const float*)d_in[0];
  const int*   ei  = (const int*)  d_in[1];
  const float* ew  = (const float*)d_in[2];
  const float* W1  = (const float*)d_in[3];
  const float* b1  = (const float*)d_in[4];
  const float* g1  = (const float*)d_in[5];
  const float* be1 = (const float*)d_in[6];
  const float* W2  = (const float*)d_in[7];
  const float* b2  = (const float*)d_in[8];
  const float* g2  = (const float*)d_in[9];
  const float* be2 = (const float*)d_in[10];
  const float* W3  = (const float*)d_in[11];
  const float* b3  = (const float*)d_in[12];
  const float* g3  = (const float*)d_in[13];
  const float* be3 = (const float*)d_in[14];
  const float* Wl1 = (const float*)d_in[15];
  const float* bl1 = (const float*)d_in[16];
  const float* Wl2 = (const float*)d_in[17];
  const float* bl2 = (const float*)d_in[18];
  const int* src = ei;
  const int* dst = ei + NE;

  // ---- workspace: 2-slot rotation, total ~220 MB (proven budget) ----
  char* p = (char*)d_ws;
  auto carve = [&](size_t bytes)->void*{
    void* r = (void*)p;
    p += (bytes + 255) & ~(size_t)255;
    return r;
  };
  float*    dinv    = (float*)   carve((size_t)NN*4);
  int*      rp      = (int*)     carve((size_t)(NN+1)*4);
  int*      fill    = (int*)     carve((size_t)NN*4);    // counts, then cursor
  int*      bsum    = (int*)     carve(256*4);
  float*    stats   = (float*)   carve(1024*4);
  u64*      acc64   = (u64*)     carve((size_t)NN*8);
  int2*     csr_sw  = (int2*)    carve((size_t)NE*8);
  float*    S1      = (float*)   carve((size_t)NN*256*4);   // 102.4 MB slot
  float*    S2      = (float*)   carve((size_t)NN*256*4);   // 102.4 MB slot
  ushort_t* W1tH    = (ushort_t*)carve(128*256*2);
  ushort_t* W1tL    = (ushort_t*)carve(128*256*2);
  ushort_t* W2tH    = (ushort_t*)carve(256*256*2);
  ushort_t* W2tL    = (ushort_t*)carve(256*256*2);
  ushort_t* W3tH    = (ushort_t*)carve(256*256*2);
  ushort_t* W3tL    = (ushort_t*)carve(256*256*2);
  ushort_t* Wl1tH   = (ushort_t*)carve(256*256*2);
  ushort_t* Wl1tL   = (ushort_t*)carve(256*256*2);
  ushort_t* Wl2tH   = (ushort_t*)carve(256*32*2);
  ushort_t* Wl2tL   = (ushort_t*)carve(256*32*2);

  // split views of the two slots (hi array then lo array within one slot)
  ushort_t* S1h256 = (ushort_t*)S1;  ushort_t* S1l256 = S1h256 + (size_t)NN*256;
  ushort_t* S2h256 = (ushort_t*)S2;  ushort_t* S2l256 = S2h256 + (size_t)NN*256;
  ushort_t* S1h128 = (ushort_t*)S1;  ushort_t* S1l128 = S1h128 + (size_t)NN*128;  // ax split (K=128)

  const int nb = (NN + 1023) / 1024;
  const int spmm_blocks = (NN + 3) / 4;

  // graph preprocessing (shared by all 3 conv layers)
  zero_acc<<<(NN+255)/256, 256, 0, stream>>>(acc64, NN);
  edge_hist<<<(NE+255)/256, 256, 0, stream>>>(dst, ew, acc64, NE);
  finalize_acc<<<(NN+255)/256, 256, 0, stream>>>(acc64, dinv, fill, NN);
  scan_block<<<nb, 1024, 0, stream>>>(fill, rp, bsum, NN);
  scan_small<<<1, 128, 0, stream>>>(bsum, nb);
  scan_add<<<nb, 1024, 0, stream>>>(rp, fill, bsum, NN, NE);
  fill_csr_k<<<(NE+255)/256, 256, 0, stream>>>(src, dst, ew, dinv, fill, csr_sw, NE);

  // weight splits
  wsplit<<<(128*256+255)/256, 256, 0, stream>>>(W1,  W1tH,  W1tL,  128, 256);
  wsplit<<<(256*256+255)/256, 256, 0, stream>>>(W2,  W2tH,  W2tL,  256, 256);
  wsplit<<<(256*256+255)/256, 256, 0, stream>>>(W3,  W3tH,  W3tL,  256, 256);
  wsplit<<<(256*256+255)/256, 256, 0, stream>>>(Wl1, Wl1tH, Wl1tL, 256, 256);
  wsplit<<<(256*32 +255)/256, 256, 0, stream>>>(Wl2, Wl2tH, Wl2tL, 256, 32);

  dim3 gridBig((NN+127)/128, 2);
  dim3 gridOut((NN+127)/128, 1);

  auto run_bn = [&](const float* fin, ushort_t* hi, ushort_t* lo,
                    const float* g, const float* be){
    zero_stats<<<1, 512, 0, stream>>>(stats);
    bn_partial<<<(NN+255)/256, 256, 0, stream>>>(fin, stats, NN);
    bn_final<<<1, 256, 0, stream>>>(stats, g, be, NN);
    bn_apply_split<<<(int)(((size_t)NN*64 + 255)/256), 256, 0, stream>>>(fin, stats, hi, lo, NN);
  };

  // conv1 (aggregate-first): spmm over x (128 ch) emits split directly -> S1 ;
  // gemm+b1 -> S2 fp32 ; bn -> S1 splits
  spmm_x<<<spmm_blocks, 256, 0, stream>>>(x, rp, csr_sw, dinv, S1h128, S1l128, NN);
  gemm_mfma<128,128,64,64,2,0><<<gridBig, 256, 0, stream>>>(
      S1h128, S1l128, W1tH, W1tL, b1, S2, nullptr, nullptr, NN, 128, 256);
  run_bn(S2, S1h256, S1l256, g1, be1);

  // conv2: gemm S1(split) -> S2 fp32 ; spmm full-width S2 -> S1 ; bn S1 -> S2 split
  gemm_mfma<128,128,64,64,0,0><<<gridBig, 256, 0, stream>>>(
      S1h256, S1l256, W2tH, W2tL, nullptr, S2, nullptr, nullptr, NN, 256, 256);
  spmm_full<<<spmm_blocks, 256, 0, stream>>>(S2, rp, csr_sw, dinv, b2, S1, NN);
  run_bn(S1, S2h256, S2l256, g2, be2);

  // conv3: gemm S2(split) -> S1 fp32 ; spmm S1 -> S2 ; bn S2 -> S1 split
  gemm_mfma<128,128,64,64,0,0><<<gridBig, 256, 0, stream>>>(
      S2h256, S2l256, W3tH, W3tL, nullptr, S1, nullptr, nullptr, NN, 256, 256);
  spmm_full<<<spmm_blocks, 256, 0, stream>>>(S1, rp, csr_sw, dinv, b3, S2, NN);
  run_bn(S2, S1h256, S1l256, g3, be3);

  // head: leaky(h @ Wl1 + bl1) -> S2 split ; then @ Wl2 + bl2 -> d_out
  gemm_mfma<128,128,64,64,1,1><<<gridBig, 256, 0, stream>>>(
      S1h256, S1l256, Wl1tH, Wl1tL, bl1, nullptr, S2h256, S2l256, NN, 256, 256);
  gemm_mfma<128,32,32,32,2,0><<<gridOut, 256, 0, stream>>>(
      S2h256, S2l256, Wl2tH, Wl2tL, bl2, (float*)d_out, nullptr, nullptr, NN, 256, 32);
}

// Round 8
// 1203.082 us; speedup vs baseline: 1.3096x; 1.3096x over previous
//
#include <hip/hip_runtime.h>

#define NN 100000
#define NE 1600000
#define EPS_BN 1e-5f

typedef unsigned short ushort_t;
typedef unsigned long long u64;
typedef _Float16 f16;
typedef short v8s __attribute__((ext_vector_type(8)));     // 8 bf16 (4 VGPR)
typedef float v4f __attribute__((ext_vector_type(4)));     // 4 fp32 acc
typedef f16 f16x2 __attribute__((ext_vector_type(2)));
typedef f16 f16x4 __attribute__((ext_vector_type(4)));

__device__ __forceinline__ float lk(float x){ return x >= 0.f ? x : 0.1f*x; }

__device__ __forceinline__ ushort_t f2bf(float x){
  unsigned u = __float_as_uint(x);
  unsigned r = (u + 0x7fffu + ((u >> 16) & 1u)) >> 16;
  return (ushort_t)r;
}
__device__ __forceinline__ float bf2f(ushort_t h){
  return __uint_as_float(((unsigned)h) << 16);
}
__device__ __forceinline__ void split2(float x, ushort_t& hi, ushort_t& lo){
  hi = f2bf(x);
  lo = f2bf(x - bf2f(hi));
}

// async 16B global->LDS (lds dst is wave-uniform base; HW adds lane*16)
__device__ __forceinline__ void gload16(const ushort_t* g, ushort_t* l){
  __builtin_amdgcn_global_load_lds((const __attribute__((address_space(1))) void*)g,
                                   (__attribute__((address_space(3))) void*)l, 16, 0, 0);
}

// ---------------- degree+count histogram: ONE packed u64 atomic per edge ----------------
__global__ void zero_acc(u64* __restrict__ acc, int n){
  int i = blockIdx.x*256 + threadIdx.x;
  if (i < n) acc[i] = 0ull;
}

__global__ void edge_hist(const int* __restrict__ dst, const float* __restrict__ ew,
                          u64* __restrict__ acc, int e){
  int i = blockIdx.x*256 + threadIdx.x;
  if (i < e){
    int d = dst[i];
    unsigned fx = (unsigned)(ew[i] * 67108864.0f + 0.5f);   // 2^26 fixed point
    atomicAdd(&acc[d], (1ull << 40) | (u64)fx);
  }
}

__global__ void finalize_acc(const u64* __restrict__ acc, float* __restrict__ dinv,
                             int* __restrict__ cnt, int n){
  int i = blockIdx.x*256 + threadIdx.x;
  if (i < n){
    u64 v = acc[i];
    cnt[i] = (int)(v >> 40);
    double w = (double)(v & 0xFFFFFFFFFFull) * (1.0/67108864.0);
    dinv[i] = rsqrtf((float)(1.0 + w));   // +1 self loop
  }
}

// ---------------- exclusive scan (3-kernel) ----------------
__global__ __launch_bounds__(1024) void scan_block(const int* __restrict__ in, int* __restrict__ out,
                                                   int* __restrict__ bsum, int n){
  __shared__ int s[1024];
  int t = threadIdx.x;
  int i = blockIdx.x*1024 + t;
  int v = (i < n) ? in[i] : 0;
  s[t] = v; __syncthreads();
  for (int off = 1; off < 1024; off <<= 1){
    int x = (t >= off) ? s[t-off] : 0;
    __syncthreads();
    s[t] += x;
    __syncthreads();
  }
  if (i < n) out[i] = s[t] - v;
  if (t == 1023) bsum[blockIdx.x] = s[1023];
}

__global__ void scan_small(int* __restrict__ bsum, int nb){
  __shared__ int s[128];
  int t = threadIdx.x;
  int v = (t < nb) ? bsum[t] : 0;
  s[t] = v; __syncthreads();
  for (int off = 1; off < 128; off <<= 1){
    int x = (t >= off) ? s[t-off] : 0;
    __syncthreads();
    s[t] += x;
    __syncthreads();
  }
  if (t < nb) bsum[t] = s[t] - v;
}

__global__ __launch_bounds__(1024) void scan_add(int* __restrict__ rp, int* __restrict__ fill,
                                                 const int* __restrict__ bsum, int n, int etot){
  int i = blockIdx.x*1024 + threadIdx.x;
  if (i < n){
    int v = rp[i] + bsum[blockIdx.x];
    rp[i] = v;
    fill[i] = v;
  }
  if (i == 0) rp[n] = etot;
}

// ---------------- CSR fill: one scattered 8B store per edge ----------------
__global__ void fill_csr_k(const int* __restrict__ src, const int* __restrict__ dst,
                           const float* __restrict__ ew, const float* __restrict__ dinv,
                           int* __restrict__ fill, int2* __restrict__ csr_sw, int e){
  int i = blockIdx.x*256 + threadIdx.x;
  if (i >= e) return;
  int s = src[i], d = dst[i];
  int pos = atomicAdd(&fill[d], 1);
  float w = dinv[s] * ew[i] * dinv[d];
  csr_sw[pos] = make_int2(s, __float_as_int(w));
}

// ---------------- x fp32 -> fp16 convert ----------------
__global__ void cvt_x(const float* __restrict__ in, f16* __restrict__ out, int n4){
  int i = blockIdx.x*256 + threadIdx.x;
  if (i >= n4) return;
  float4 v = ((const float4*)in)[i];
  f16x4 h = (f16x4){(f16)v.x, (f16)v.y, (f16)v.z, (f16)v.w};
  ((f16x4*)out)[i] = h;
}

// ---------------- SpMM full-width (256 ch), fp16 gather, fp32 accumulate ----------------
// Gathered rows are fp16 (512B/row): halves the L2-fill traffic, which is at its
// compulsory floor for fp32 (~7 XCDs x 102MB). One wave per node, 4 ch/lane.
__global__ __launch_bounds__(256) void spmm16(const f16* __restrict__ h,
    const int* __restrict__ rp, const int2* __restrict__ csr_sw,
    const float* __restrict__ dinv, const float* __restrict__ bias,
    float* __restrict__ out, int n){
  int node = blockIdx.x*4 + (threadIdx.x >> 6);
  node = __builtin_amdgcn_readfirstlane(node);   // wave-uniform -> scalarize CSR loads
  if (node >= n) return;
  int lane = threadIdx.x & 63;
  const f16* hb = h + lane*4;
  float di = dinv[node];
  float c0 = di * di;
  f16x4 hv = *(const f16x4*)(hb + (size_t)node*256);
  float4 bb = *(const float4*)(bias + lane*4);
  float ax = fmaf(c0, (float)hv[0], bb.x);
  float ay = fmaf(c0, (float)hv[1], bb.y);
  float az = fmaf(c0, (float)hv[2], bb.z);
  float aw = fmaf(c0, (float)hv[3], bb.w);
  int p = rp[node], pend = rp[node+1];
  for (; p + 4 <= pend; p += 4){
    int2 e0 = csr_sw[p],   e1 = csr_sw[p+1], e2 = csr_sw[p+2], e3 = csr_sw[p+3];
    f16x4 v0 = *(const f16x4*)(hb + (size_t)e0.x*256);
    f16x4 v1 = *(const f16x4*)(hb + (size_t)e1.x*256);
    f16x4 v2 = *(const f16x4*)(hb + (size_t)e2.x*256);
    f16x4 v3 = *(const f16x4*)(hb + (size_t)e3.x*256);
    float w0 = __int_as_float(e0.y), w1 = __int_as_float(e1.y);
    float w2 = __int_as_float(e2.y), w3 = __int_as_float(e3.y);
    ax = fmaf(w0, (float)v0[0], ax); ay = fmaf(w0, (float)v0[1], ay);
    az = fmaf(w0, (float)v0[2], az); aw = fmaf(w0, (float)v0[3], aw);
    ax = fmaf(w1, (float)v1[0], ax); ay = fmaf(w1, (float)v1[1], ay);
    az = fmaf(w1, (float)v1[2], az); aw = fmaf(w1, (float)v1[3], aw);
    ax = fmaf(w2, (float)v2[0], ax); ay = fmaf(w2, (float)v2[1], ay);
    az = fmaf(w2, (float)v2[2], az); aw = fmaf(w2, (float)v2[3], aw);
    ax = fmaf(w3, (float)v3[0], ax); ay = fmaf(w3, (float)v3[1], ay);
    az = fmaf(w3, (float)v3[2], az); aw = fmaf(w3, (float)v3[3], aw);
  }
  for (; p < pend; ++p){
    int2 e = csr_sw[p];
    float w = __int_as_float(e.y);
    f16x4 v = *(const f16x4*)(hb + (size_t)e.x*256);
    ax = fmaf(w, (float)v[0], ax); ay = fmaf(w, (float)v[1], ay);
    az = fmaf(w, (float)v[2], az); aw = fmaf(w, (float)v[3], aw);
  }
  *(float4*)(out + (size_t)node*256 + lane*4) = make_float4(ax, ay, az, aw);
}

// ---------------- conv1 SpMM: 128 ch over fp16 x, epilogue emits bf16 hi/lo split ----------------
__global__ __launch_bounds__(256) void spmm_x16(const f16* __restrict__ h,
    const int* __restrict__ rp, const int2* __restrict__ csr_sw,
    const float* __restrict__ dinv,
    ushort_t* __restrict__ ohi, ushort_t* __restrict__ olo, int n){
  int node = blockIdx.x*4 + (threadIdx.x >> 6);
  node = __builtin_amdgcn_readfirstlane(node);
  if (node >= n) return;
  int lane = threadIdx.x & 63;
  const f16* hb = h + lane*2;
  float di = dinv[node];
  float c0 = di * di;
  f16x2 hv = *(const f16x2*)(hb + (size_t)node*128);
  float ax = c0 * (float)hv[0];
  float ay = c0 * (float)hv[1];
  int p = rp[node], pend = rp[node+1];
  for (; p + 8 <= pend; p += 8){
    int2 e0 = csr_sw[p],   e1 = csr_sw[p+1], e2 = csr_sw[p+2], e3 = csr_sw[p+3];
    int2 e4 = csr_sw[p+4], e5 = csr_sw[p+5], e6 = csr_sw[p+6], e7 = csr_sw[p+7];
    f16x2 v0 = *(const f16x2*)(hb + (size_t)e0.x*128);
    f16x2 v1 = *(const f16x2*)(hb + (size_t)e1.x*128);
    f16x2 v2 = *(const f16x2*)(hb + (size_t)e2.x*128);
    f16x2 v3 = *(const f16x2*)(hb + (size_t)e3.x*128);
    f16x2 v4 = *(const f16x2*)(hb + (size_t)e4.x*128);
    f16x2 v5 = *(const f16x2*)(hb + (size_t)e5.x*128);
    f16x2 v6 = *(const f16x2*)(hb + (size_t)e6.x*128);
    f16x2 v7 = *(const f16x2*)(hb + (size_t)e7.x*128);
    ax = fmaf(__int_as_float(e0.y), (float)v0[0], ax); ay = fmaf(__int_as_float(e0.y), (float)v0[1], ay);
    ax = fmaf(__int_as_float(e1.y), (float)v1[0], ax); ay = fmaf(__int_as_float(e1.y), (float)v1[1], ay);
    ax = fmaf(__int_as_float(e2.y), (float)v2[0], ax); ay = fmaf(__int_as_float(e2.y), (float)v2[1], ay);
    ax = fmaf(__int_as_float(e3.y), (float)v3[0], ax); ay = fmaf(__int_as_float(e3.y), (float)v3[1], ay);
    ax = fmaf(__int_as_float(e4.y), (float)v4[0], ax); ay = fmaf(__int_as_float(e4.y), (float)v4[1], ay);
    ax = fmaf(__int_as_float(e5.y), (float)v5[0], ax); ay = fmaf(__int_as_float(e5.y), (float)v5[1], ay);
    ax = fmaf(__int_as_float(e6.y), (float)v6[0], ax); ay = fmaf(__int_as_float(e6.y), (float)v6[1], ay);
    ax = fmaf(__int_as_float(e7.y), (float)v7[0], ax); ay = fmaf(__int_as_float(e7.y), (float)v7[1], ay);
  }
  for (; p < pend; ++p){
    int2 e = csr_sw[p];
    float w = __int_as_float(e.y);
    f16x2 v = *(const f16x2*)(hb + (size_t)e.x*128);
    ax = fmaf(w, (float)v[0], ax); ay = fmaf(w, (float)v[1], ay);
  }
  ushort_t hx, lx, hy, ly;
  split2(ax, hx, lx);
  split2(ay, hy, ly);
  size_t o = (size_t)node*128 + lane*2;
  ohi[o] = hx; ohi[o+1] = hy;
  olo[o] = lx; olo[o+1] = ly;
}

// ---------------- BatchNorm ----------------
__global__ void zero_stats(float* __restrict__ stats){
  stats[threadIdx.x] = 0.f;   // 512 threads
}

__global__ __launch_bounds__(256) void bn_partial(const float* __restrict__ a,
                                                  float* __restrict__ stats, int n){
  int c = threadIdx.x;
  int r0 = blockIdx.x * 256;
  int rend = min(r0 + 256, n);
  float s = 0.f, s2 = 0.f;
  for (int r = r0; r < rend; ++r){
    float v = a[(size_t)r*256 + c];
    s += v;
    s2 = fmaf(v, v, s2);
  }
  atomicAdd(&stats[c], s);
  atomicAdd(&stats[256 + c], s2);
}

__global__ void bn_final(float* __restrict__ stats, const float* __restrict__ g,
                         const float* __restrict__ be, int n){
  int c = threadIdx.x;
  float inv_n = 1.0f / (float)n;
  float mean = stats[c] * inv_n;
  float var  = fmaxf(stats[256 + c] * inv_n - mean*mean, 0.f);
  float sc   = g[c] * rsqrtf(var + EPS_BN);
  stats[512 + c] = sc;
  stats[768 + c] = be[c] - mean * sc;
}

// bn scale/shift + leaky, emit hi/lo bf16 split directly (feeds next MFMA GEMM)
__global__ __launch_bounds__(256) void bn_apply_split(const float* __restrict__ a,
    const float* __restrict__ stats, ushort_t* __restrict__ hi, ushort_t* __restrict__ lo, int n){
  size_t i = (size_t)blockIdx.x*256 + threadIdx.x;   // one float4 per thread
  if (i >= (size_t)n*64) return;
  int c4 = (int)(i & 63);
  float4 v  = ((const float4*)a)[i];
  float4 sc = ((const float4*)(stats + 512))[c4];
  float4 sh = ((const float4*)(stats + 768))[c4];
  v.x = lk(fmaf(v.x, sc.x, sh.x));
  v.y = lk(fmaf(v.y, sc.y, sh.y));
  v.z = lk(fmaf(v.z, sc.z, sh.z));
  v.w = lk(fmaf(v.w, sc.w, sh.w));
  ushort4 h, l;
  split2(v.x, h.x, l.x); split2(v.y, h.y, l.y);
  split2(v.z, h.z, l.z); split2(v.w, h.w, l.w);
  ((ushort4*)hi)[i] = h;
  ((ushort4*)lo)[i] = l;
}

// W[K][M] fp32 -> transposed split WtHi/WtLo[M][K] bf16
__global__ void wsplit(const float* __restrict__ W, ushort_t* __restrict__ hiT,
                       ushort_t* __restrict__ loT, int K, int M){
  int i = blockIdx.x*256 + threadIdx.x;
  if (i >= K*M) return;
  int k = i / M, m = i % M;
  ushort_t h, l;
  split2(W[i], h, l);
  hiT[(size_t)m*K + k] = h;
  loT[(size_t)m*K + k] = l;
}

// ---------------- bf16x3 split MFMA GEMM ----------------
// C[n,M] = (Ahi+Alo)[n,K] @ (Bhi+Blo)^T  with B stored transposed [M][K].
// ACT: 0 none ; 1 bias+leaky ; 2 bias.
// OMODE: 0 fp32->Cf ; 1 split bf16->Chi/Clo ; 2 fp16->Ch
template<int BM, int BN, int WM, int WN, int ACT, int OMODE>
__global__ __launch_bounds__(256) void gemm_mfma(
    const ushort_t* __restrict__ Ahi_g, const ushort_t* __restrict__ Alo_g,
    const ushort_t* __restrict__ Bhi_g, const ushort_t* __restrict__ Blo_g,
    const float* __restrict__ bias,
    float* __restrict__ Cf, ushort_t* __restrict__ Chi, ushort_t* __restrict__ Clo,
    f16* __restrict__ Ch,
    int nrows, int K, int M){
  constexpr int FI = WM/16, FJ = WN/16;
  constexpr int WCOLS = BN/WN;
  __shared__ ushort_t sAhi[BM*32];
  __shared__ ushort_t sAlo[BM*32];
  __shared__ ushort_t sBhi[BN*32];
  __shared__ ushort_t sBlo[BN*32];
  const int tid  = threadIdx.x;
  const int wave = tid >> 6;
  const int lane = tid & 63;
  const int r0 = blockIdx.x * BM;
  const int c0 = blockIdx.y * BN;
  const int wr0 = (wave / WCOLS) * WM;
  const int wc0 = (wave % WCOLS) * WN;
  const int m = lane & 15, q = lane >> 4;

  v4f acc[FI][FJ];
#pragma unroll
  for (int i = 0; i < FI; ++i)
#pragma unroll
    for (int j = 0; j < FJ; ++j) acc[i][j] = (v4f){0.f,0.f,0.f,0.f};

  const int srow = lane >> 2;                        // row within 16-row chunk
  const int kqlog = (lane & 3) ^ ((srow >> 1) & 3);  // swizzled logical 16B chunk
  const int fsw = (q ^ ((m >> 1) & 3)) * 8;          // frag read: swizzled k elem offset

  for (int kt = 0; kt < K; kt += 32){
#pragma unroll
    for (int c = 0; c < BM/64; ++c){                 // each wave stages BM/64 16-row A-chunks
      int cc = c*4 + wave;
      int gr = r0 + cc*16 + srow;
      gr = min(gr, nrows - 1);
      size_t go = (size_t)gr*K + kt + kqlog*8;
      gload16(Ahi_g + go, &sAhi[cc*512]);
      gload16(Alo_g + go, &sAlo[cc*512]);
    }
    for (int cc = wave; cc < BN/16; cc += 4){
      int gr = c0 + cc*16 + srow;
      size_t go = (size_t)gr*K + kt + kqlog*8;
      gload16(Bhi_g + go, &sBhi[cc*512]);
      gload16(Blo_g + go, &sBlo[cc*512]);
    }
    __syncthreads();   // drains vmcnt (global_load_lds) per barrier semantics

    v8s ah[FI], al[FI], bh[FJ], bl[FJ];
#pragma unroll
    for (int i = 0; i < FI; ++i){
      int off = (wr0 + i*16 + m)*32 + fsw;
      ah[i] = *(const v8s*)&sAhi[off];
      al[i] = *(const v8s*)&sAlo[off];
    }
#pragma unroll
    for (int j = 0; j < FJ; ++j){
      int off = (wc0 + j*16 + m)*32 + fsw;
      bh[j] = *(const v8s*)&sBhi[off];
      bl[j] = *(const v8s*)&sBlo[off];
    }
#pragma unroll
    for (int i = 0; i < FI; ++i)
#pragma unroll
      for (int j = 0; j < FJ; ++j){
        acc[i][j] = __builtin_amdgcn_mfma_f32_16x16x32_bf16(ah[i], bh[j], acc[i][j], 0, 0, 0);
        acc[i][j] = __builtin_amdgcn_mfma_f32_16x16x32_bf16(ah[i], bl[j], acc[i][j], 0, 0, 0);
        acc[i][j] = __builtin_amdgcn_mfma_f32_16x16x32_bf16(al[i], bh[j], acc[i][j], 0, 0, 0);
      }
    __syncthreads();
  }

  // epilogue: C/D layout col = lane&15, row = (lane>>4)*4 + reg  [m89/m91]
#pragma unroll
  for (int i = 0; i < FI; ++i){
#pragma unroll
    for (int j = 0; j < FJ; ++j){
      int col = c0 + wc0 + j*16 + m;
      float bv = (ACT >= 1) ? bias[col] : 0.f;
#pragma unroll
      for (int r = 0; r < 4; ++r){
        int row = r0 + wr0 + i*16 + q*4 + r;
        if (row >= nrows) continue;
        float v = acc[i][j][r] + bv;
        if (ACT == 1) v = lk(v);
        size_t o = (size_t)row*M + col;
        if (OMODE == 1){
          ushort_t h, l; split2(v, h, l);
          Chi[o] = h; Clo[o] = l;
        } else if (OMODE == 2){
          Ch[o] = (f16)v;
        } else {
          Cf[o] = v;
        }
      }
    }
  }
}

// ---------------- launch ----------------
extern "C" void kernel_launch(void* const* d_in, const int* in_sizes, int n_in,
                              void* d_out, int out_size, void* d_ws, size_t ws_size,
                              hipStream_t stream){
  const float* x   = (const float*)d_in[0];
  const int*   ei  = (const int*)  d_in[1];
  const float* ew  = (const float*)d_in[2];
  const float* W1  = (const float*)d_in[3];
  const float* b1  = (const float*)d_in[4];
  const float* g1  = (const float*)d_in[5];
  const float* be1 = (const float*)d_in[6];
  const float* W2  = (const float*)d_in[7];
  const float* b2  = (const float*)d_in[8];
  const float* g2  = (const float*)d_in[9];
  const float* be2 = (const float*)d_in[10];
  const float* W3  = (const float*)d_in[11];
  const float* b3  = (const float*)d_in[12];
  const float* g3  = (const float*)d_in[13];
  const float* be3 = (const float*)d_in[14];
  const float* Wl1 = (const float*)d_in[15];
  const float* bl1 = (const float*)d_in[16];
  const float* Wl2 = (const float*)d_in[17];
  const float* bl2 = (const float*)d_in[18];
  const int* src = ei;
  const int* dst = ei + NE;

  // ---- workspace: 2-slot rotation + in-slot fp16 aliases, total ~222 MB ----
  char* p = (char*)d_ws;
  auto carve = [&](size_t bytes)->void*{
    void* r = (void*)p;
    p += (bytes + 255) & ~(size_t)255;
    return r;
  };
  float*    dinv    = (float*)   carve((size_t)NN*4);
  int*      rp      = (int*)     carve((size_t)(NN+1)*4);
  int*      fill    = (int*)     carve((size_t)NN*4);    // counts, then cursor
  int*      bsum    = (int*)     carve(256*4);
  float*    stats   = (float*)   carve(1024*4);
  u64*      acc64   = (u64*)     carve((size_t)NN*8);
  int2*     csr_sw  = (int2*)    carve((size_t)NE*8);
  float*    S1      = (float*)   carve((size_t)NN*256*4);   // 102.4 MB slot
  float*    S2      = (float*)   carve((size_t)NN*256*4);   // 102.4 MB slot
  ushort_t* W1tH    = (ushort_t*)carve(128*256*2);
  ushort_t* W1tL    = (ushort_t*)carve(128*256*2);
  ushort_t* W2tH    = (ushort_t*)carve(256*256*2);
  ushort_t* W2tL    = (ushort_t*)carve(256*256*2);
  ushort_t* W3tH    = (ushort_t*)carve(256*256*2);
  ushort_t* W3tL    = (ushort_t*)carve(256*256*2);
  ushort_t* Wl1tH   = (ushort_t*)carve(256*256*2);
  ushort_t* Wl1tL   = (ushort_t*)carve(256*256*2);
  ushort_t* Wl2tH   = (ushort_t*)carve(256*32*2);
  ushort_t* Wl2tL   = (ushort_t*)carve(256*32*2);

  // aliased views (stream-order makes each safe; see per-layer notes below)
  ushort_t* S1h256 = (ushort_t*)S1;  ushort_t* S1l256 = S1h256 + (size_t)NN*256;
  ushort_t* S2h256 = (ushort_t*)S2;  ushort_t* S2l256 = S2h256 + (size_t)NN*256;
  ushort_t* S1h128 = (ushort_t*)S1;  ushort_t* S1l128 = S1h128 + (size_t)NN*128;
  f16*      x16    = (f16*)S2;            // 25.6 MB, dead once spmm_x16 done
  f16*      H2f16  = (f16*)S2;            // conv2 gemm out, 51.2 MB, dead once spmm16 done
  f16*      H3f16  = (f16*)S1;            // conv3 gemm out, 51.2 MB, dead once spmm16 done

  const int nb = (NN + 1023) / 1024;
  const int spmm_blocks = (NN + 3) / 4;

  // graph preprocessing (shared by all 3 conv layers)
  zero_acc<<<(NN+255)/256, 256, 0, stream>>>(acc64, NN);
  edge_hist<<<(NE+255)/256, 256, 0, stream>>>(dst, ew, acc64, NE);
  finalize_acc<<<(NN+255)/256, 256, 0, stream>>>(acc64, dinv, fill, NN);
  scan_block<<<nb, 1024, 0, stream>>>(fill, rp, bsum, NN);
  scan_small<<<1, 128, 0, stream>>>(bsum, nb);
  scan_add<<<nb, 1024, 0, stream>>>(rp, fill, bsum, NN, NE);
  fill_csr_k<<<(NE+255)/256, 256, 0, stream>>>(src, dst, ew, dinv, fill, csr_sw, NE);

  // weight splits
  wsplit<<<(128*256+255)/256, 256, 0, stream>>>(W1,  W1tH,  W1tL,  128, 256);
  wsplit<<<(256*256+255)/256, 256, 0, stream>>>(W2,  W2tH,  W2tL,  256, 256);
  wsplit<<<(256*256+255)/256, 256, 0, stream>>>(W3,  W3tH,  W3tL,  256, 256);
  wsplit<<<(256*256+255)/256, 256, 0, stream>>>(Wl1, Wl1tH, Wl1tL, 256, 256);
  wsplit<<<(256*32 +255)/256, 256, 0, stream>>>(Wl2, Wl2tH, Wl2tL, 256, 32);

  dim3 gridBig((NN+127)/128, 2);
  dim3 gridOut((NN+127)/128, 1);

  auto run_bn = [&](const float* fin, ushort_t* hi, ushort_t* lo,
                    const float* g, const float* be){
    zero_stats<<<1, 512, 0, stream>>>(stats);
    bn_partial<<<(NN+255)/256, 256, 0, stream>>>(fin, stats, NN);
    bn_final<<<1, 256, 0, stream>>>(stats, g, be, NN);
    bn_apply_split<<<(int)(((size_t)NN*64 + 255)/256), 256, 0, stream>>>(fin, stats, hi, lo, NN);
  };

  // conv1 (aggregate-first): x->fp16 (x16 in S2) ; spmm gather fp16 -> bf16 split in S1 ;
  // gemm+b1 -> S2 fp32 (clobbers dead x16) ; bn -> S1 split
  cvt_x<<<(NN*32+255)/256, 256, 0, stream>>>(x, x16, NN*32);
  spmm_x16<<<spmm_blocks, 256, 0, stream>>>(x16, rp, csr_sw, dinv, S1h128, S1l128, NN);
  gemm_mfma<128,128,64,64,2,0><<<gridBig, 256, 0, stream>>>(
      S1h128, S1l128, W1tH, W1tL, b1, S2, nullptr, nullptr, nullptr, NN, 128, 256);
  run_bn(S2, S1h256, S1l256, g1, be1);

  // conv2: gemm S1 split -> fp16 H in S2[0:51MB] ; spmm16 H -> S1 fp32 (gemm input dead) ;
  // bn S1 -> S2 split (H dead)
  gemm_mfma<128,128,64,64,0,2><<<gridBig, 256, 0, stream>>>(
      S1h256, S1l256, W2tH, W2tL, nullptr, nullptr, nullptr, nullptr, H2f16, NN, 256, 256);
  spmm16<<<spmm_blocks, 256, 0, stream>>>(H2f16, rp, csr_sw, dinv, b2, S1, NN);
  run_bn(S1, S2h256, S2l256, g2, be2);

  // conv3: gemm S2 split -> fp16 H in S1[0:51MB] ; spmm16 H -> S2 fp32 ; bn S2 -> S1 split
  gemm_mfma<128,128,64,64,0,2><<<gridBig, 256, 0, stream>>>(
      S2h256, S2l256, W3tH, W3tL, nullptr, nullptr, nullptr, nullptr, H3f16, NN, 256, 256);
  spmm16<<<spmm_blocks, 256, 0, stream>>>(H3f16, rp, csr_sw, dinv, b3, S2, NN);
  run_bn(S2, S1h256, S1l256, g3, be3);

  // head: leaky(h @ Wl1 + bl1) -> S2 split ; then @ Wl2 + bl2 -> d_out
  gemm_mfma<128,128,64,64,1,1><<<gridBig, 256, 0, stream>>>(
      S1h256, S1l256, Wl1tH, Wl1tL, bl1, nullptr, S2h256, S2l256, nullptr, NN, 256, 256);
  gemm_mfma<128,32,32,32,2,0><<<gridOut, 256, 0, stream>>>(
      S2h256, S2l256, Wl2tH, Wl2tL, bl2, (float*)d_out, nullptr, nullptr, nullptr, NN, 256, 32);
}

// Round 9
// 1164.487 us; speedup vs baseline: 1.3530x; 1.0331x over previous
//
#include <hip/hip_runtime.h>

#define NN 100000
#define NE 1600000
#define EPS_BN 1e-5f

typedef unsigned short ushort_t;
typedef unsigned long long u64;
typedef _Float16 f16;
typedef short v8s __attribute__((ext_vector_type(8)));     // 8 bf16 (4 VGPR)
typedef float v4f __attribute__((ext_vector_type(4)));     // 4 fp32 acc
typedef f16 f16x2 __attribute__((ext_vector_type(2)));
typedef f16 f16x4 __attribute__((ext_vector_type(4)));

__device__ __forceinline__ float lk(float x){ return x >= 0.f ? x : 0.1f*x; }

__device__ __forceinline__ ushort_t f2bf(float x){
  unsigned u = __float_as_uint(x);
  unsigned r = (u + 0x7fffu + ((u >> 16) & 1u)) >> 16;
  return (ushort_t)r;
}
__device__ __forceinline__ float bf2f(ushort_t h){
  return __uint_as_float(((unsigned)h) << 16);
}
__device__ __forceinline__ void split2(float x, ushort_t& hi, ushort_t& lo){
  hi = f2bf(x);
  lo = f2bf(x - bf2f(hi));
}

// async 16B global->LDS (lds dst is wave-uniform base; HW adds lane*16)
__device__ __forceinline__ void gload16(const ushort_t* g, ushort_t* l){
  __builtin_amdgcn_global_load_lds((const __attribute__((address_space(1))) void*)g,
                                   (__attribute__((address_space(3))) void*)l, 16, 0, 0);
}

// ---------------- degree+count histogram: ONE packed u64 atomic per edge ----------------
// Returns old value -> (old>>40) is this edge's rank within its dst bucket (used by
// the atomic-free CSR fill).
__global__ void zero_acc(u64* __restrict__ acc, int n){
  int i = blockIdx.x*256 + threadIdx.x;
  if (i < n) acc[i] = 0ull;
}

__global__ void edge_hist(const int* __restrict__ dst, const float* __restrict__ ew,
                          u64* __restrict__ acc, ushort_t* __restrict__ rank, int e){
  int i = blockIdx.x*256 + threadIdx.x;
  if (i < e){
    int d = dst[i];
    unsigned fx = (unsigned)(ew[i] * 67108864.0f + 0.5f);   // 2^26 fixed point
    u64 old = atomicAdd(&acc[d], (1ull << 40) | (u64)fx);
    rank[i] = (ushort_t)(old >> 40);                        // in-bucket rank, deg << 65536
  }
}

__global__ void finalize_acc(const u64* __restrict__ acc, float* __restrict__ dinv,
                             int* __restrict__ cnt, int n){
  int i = blockIdx.x*256 + threadIdx.x;
  if (i < n){
    u64 v = acc[i];
    cnt[i] = (int)(v >> 40);
    double w = (double)(v & 0xFFFFFFFFFFull) * (1.0/67108864.0);
    dinv[i] = rsqrtf((float)(1.0 + w));   // +1 self loop
  }
}

// ---------------- exclusive scan (3-kernel) ----------------
__global__ __launch_bounds__(1024) void scan_block(const int* __restrict__ in, int* __restrict__ out,
                                                   int* __restrict__ bsum, int n){
  __shared__ int s[1024];
  int t = threadIdx.x;
  int i = blockIdx.x*1024 + t;
  int v = (i < n) ? in[i] : 0;
  s[t] = v; __syncthreads();
  for (int off = 1; off < 1024; off <<= 1){
    int x = (t >= off) ? s[t-off] : 0;
    __syncthreads();
    s[t] += x;
    __syncthreads();
  }
  if (i < n) out[i] = s[t] - v;
  if (t == 1023) bsum[blockIdx.x] = s[1023];
}

__global__ void scan_small(int* __restrict__ bsum, int nb){
  __shared__ int s[128];
  int t = threadIdx.x;
  int v = (t < nb) ? bsum[t] : 0;
  s[t] = v; __syncthreads();
  for (int off = 1; off < 128; off <<= 1){
    int x = (t >= off) ? s[t-off] : 0;
    __syncthreads();
    s[t] += x;
    __syncthreads();
  }
  if (t < nb) bsum[t] = s[t] - v;
}

__global__ __launch_bounds__(1024) void scan_add(int* __restrict__ rp,
                                                 const int* __restrict__ bsum, int n, int etot){
  int i = blockIdx.x*1024 + threadIdx.x;
  if (i < n) rp[i] += bsum[blockIdx.x];
  if (i == 0) rp[n] = etot;
}

// ---------------- CSR fill: atomic-free (pos = rp[d] + rank), one 8B scatter/edge ----------------
__global__ void fill_csr_k(const int* __restrict__ src, const int* __restrict__ dst,
                           const float* __restrict__ ew, const float* __restrict__ dinv,
                           const int* __restrict__ rp, const ushort_t* __restrict__ rank,
                           int2* __restrict__ csr_sw, int e){
  int i = blockIdx.x*256 + threadIdx.x;
  if (i >= e) return;
  int s = src[i], d = dst[i];
  int pos = rp[d] + (int)rank[i];
  float w = dinv[s] * ew[i] * dinv[d];
  csr_sw[pos] = make_int2(s, __float_as_int(w));
}

// ---------------- x fp32 -> fp16 convert ----------------
__global__ void cvt_x(const float* __restrict__ in, f16* __restrict__ out, int n4){
  int i = blockIdx.x*256 + threadIdx.x;
  if (i >= n4) return;
  float4 v = ((const float4*)in)[i];
  f16x4 h = (f16x4){(f16)v.x, (f16)v.y, (f16)v.z, (f16)v.w};
  ((f16x4*)out)[i] = h;
}

// ---------------- SpMM full-width (256 ch), fp16 gather, fp32 accumulate ----------------
// Unroll 8, dual accumulator chains: 8 independent gathers in flight per lane,
// 4-deep (not 8-deep) FMA dependency per accumulator.
__global__ __launch_bounds__(256) void spmm16(const f16* __restrict__ h,
    const int* __restrict__ rp, const int2* __restrict__ csr_sw,
    const float* __restrict__ dinv, const float* __restrict__ bias,
    float* __restrict__ out, int n){
  int node = blockIdx.x*4 + (threadIdx.x >> 6);
  node = __builtin_amdgcn_readfirstlane(node);   // wave-uniform -> scalarize CSR loads
  if (node >= n) return;
  int lane = threadIdx.x & 63;
  const f16* hb = h + lane*4;
  float di = dinv[node];
  float c0 = di * di;
  f16x4 hv = *(const f16x4*)(hb + (size_t)node*256);
  float4 bb = *(const float4*)(bias + lane*4);
  float ax0 = fmaf(c0, (float)hv[0], bb.x);
  float ay0 = fmaf(c0, (float)hv[1], bb.y);
  float az0 = fmaf(c0, (float)hv[2], bb.z);
  float aw0 = fmaf(c0, (float)hv[3], bb.w);
  float ax1 = 0.f, ay1 = 0.f, az1 = 0.f, aw1 = 0.f;
  int p = rp[node], pend = rp[node+1];
  for (; p + 8 <= pend; p += 8){
    int2 e0 = csr_sw[p],   e1 = csr_sw[p+1], e2 = csr_sw[p+2], e3 = csr_sw[p+3];
    int2 e4 = csr_sw[p+4], e5 = csr_sw[p+5], e6 = csr_sw[p+6], e7 = csr_sw[p+7];
    f16x4 v0 = *(const f16x4*)(hb + (size_t)e0.x*256);
    f16x4 v1 = *(const f16x4*)(hb + (size_t)e1.x*256);
    f16x4 v2 = *(const f16x4*)(hb + (size_t)e2.x*256);
    f16x4 v3 = *(const f16x4*)(hb + (size_t)e3.x*256);
    f16x4 v4 = *(const f16x4*)(hb + (size_t)e4.x*256);
    f16x4 v5 = *(const f16x4*)(hb + (size_t)e5.x*256);
    f16x4 v6 = *(const f16x4*)(hb + (size_t)e6.x*256);
    f16x4 v7 = *(const f16x4*)(hb + (size_t)e7.x*256);
    float w0 = __int_as_float(e0.y), w1 = __int_as_float(e1.y);
    float w2 = __int_as_float(e2.y), w3 = __int_as_float(e3.y);
    float w4 = __int_as_float(e4.y), w5 = __int_as_float(e5.y);
    float w6 = __int_as_float(e6.y), w7 = __int_as_float(e7.y);
    ax0 = fmaf(w0, (float)v0[0], ax0); ay0 = fmaf(w0, (float)v0[1], ay0);
    az0 = fmaf(w0, (float)v0[2], az0); aw0 = fmaf(w0, (float)v0[3], aw0);
    ax1 = fmaf(w1, (float)v1[0], ax1); ay1 = fmaf(w1, (float)v1[1], ay1);
    az1 = fmaf(w1, (float)v1[2], az1); aw1 = fmaf(w1, (float)v1[3], aw1);
    ax0 = fmaf(w2, (float)v2[0], ax0); ay0 = fmaf(w2, (float)v2[1], ay0);
    az0 = fmaf(w2, (float)v2[2], az0); aw0 = fmaf(w2, (float)v2[3], aw0);
    ax1 = fmaf(w3, (float)v3[0], ax1); ay1 = fmaf(w3, (float)v3[1], ay1);
    az1 = fmaf(w3, (float)v3[2], az1); aw1 = fmaf(w3, (float)v3[3], aw1);
    ax0 = fmaf(w4, (float)v4[0], ax0); ay0 = fmaf(w4, (float)v4[1], ay0);
    az0 = fmaf(w4, (float)v4[2], az0); aw0 = fmaf(w4, (float)v4[3], aw0);
    ax1 = fmaf(w5, (float)v5[0], ax1); ay1 = fmaf(w5, (float)v5[1], ay1);
    az1 = fmaf(w5, (float)v5[2], az1); aw1 = fmaf(w5, (float)v5[3], aw1);
    ax0 = fmaf(w6, (float)v6[0], ax0); ay0 = fmaf(w6, (float)v6[1], ay0);
    az0 = fmaf(w6, (float)v6[2], az0); aw0 = fmaf(w6, (float)v6[3], aw0);
    ax1 = fmaf(w7, (float)v7[0], ax1); ay1 = fmaf(w7, (float)v7[1], ay1);
    az1 = fmaf(w7, (float)v7[2], az1); aw1 = fmaf(w7, (float)v7[3], aw1);
  }
  for (; p < pend; ++p){
    int2 e = csr_sw[p];
    float w = __int_as_float(e.y);
    f16x4 v = *(const f16x4*)(hb + (size_t)e.x*256);
    ax0 = fmaf(w, (float)v[0], ax0); ay0 = fmaf(w, (float)v[1], ay0);
    az0 = fmaf(w, (float)v[2], az0); aw0 = fmaf(w, (float)v[3], aw0);
  }
  *(float4*)(out + (size_t)node*256 + lane*4) =
      make_float4(ax0+ax1, ay0+ay1, az0+az1, aw0+aw1);
}

// ---------------- conv1 SpMM: 128 ch over fp16 x, emits bf16 hi/lo split ----------------
__global__ __launch_bounds__(256) void spmm_x16(const f16* __restrict__ h,
    const int* __restrict__ rp, const int2* __restrict__ csr_sw,
    const float* __restrict__ dinv,
    ushort_t* __restrict__ ohi, ushort_t* __restrict__ olo, int n){
  int node = blockIdx.x*4 + (threadIdx.x >> 6);
  node = __builtin_amdgcn_readfirstlane(node);
  if (node >= n) return;
  int lane = threadIdx.x & 63;
  const f16* hb = h + lane*2;
  float di = dinv[node];
  float c0 = di * di;
  f16x2 hv = *(const f16x2*)(hb + (size_t)node*128);
  float ax0 = c0 * (float)hv[0];
  float ay0 = c0 * (float)hv[1];
  float ax1 = 0.f, ay1 = 0.f;
  int p = rp[node], pend = rp[node+1];
  for (; p + 8 <= pend; p += 8){
    int2 e0 = csr_sw[p],   e1 = csr_sw[p+1], e2 = csr_sw[p+2], e3 = csr_sw[p+3];
    int2 e4 = csr_sw[p+4], e5 = csr_sw[p+5], e6 = csr_sw[p+6], e7 = csr_sw[p+7];
    f16x2 v0 = *(const f16x2*)(hb + (size_t)e0.x*128);
    f16x2 v1 = *(const f16x2*)(hb + (size_t)e1.x*128);
    f16x2 v2 = *(const f16x2*)(hb + (size_t)e2.x*128);
    f16x2 v3 = *(const f16x2*)(hb + (size_t)e3.x*128);
    f16x2 v4 = *(const f16x2*)(hb + (size_t)e4.x*128);
    f16x2 v5 = *(const f16x2*)(hb + (size_t)e5.x*128);
    f16x2 v6 = *(const f16x2*)(hb + (size_t)e6.x*128);
    f16x2 v7 = *(const f16x2*)(hb + (size_t)e7.x*128);
    ax0 = fmaf(__int_as_float(e0.y), (float)v0[0], ax0); ay0 = fmaf(__int_as_float(e0.y), (float)v0[1], ay0);
    ax1 = fmaf(__int_as_float(e1.y), (float)v1[0], ax1); ay1 = fmaf(__int_as_float(e1.y), (float)v1[1], ay1);
    ax0 = fmaf(__int_as_float(e2.y), (float)v2[0], ax0); ay0 = fmaf(__int_as_float(e2.y), (float)v2[1], ay0);
    ax1 = fmaf(__int_as_float(e3.y), (float)v3[0], ax1); ay1 = fmaf(__int_as_float(e3.y), (float)v3[1], ay1);
    ax0 = fmaf(__int_as_float(e4.y), (float)v4[0], ax0); ay0 = fmaf(__int_as_float(e4.y), (float)v4[1], ay0);
    ax1 = fmaf(__int_as_float(e5.y), (float)v5[0], ax1); ay1 = fmaf(__int_as_float(e5.y), (float)v5[1], ay1);
    ax0 = fmaf(__int_as_float(e6.y), (float)v6[0], ax0); ay0 = fmaf(__int_as_float(e6.y), (float)v6[1], ay0);
    ax1 = fmaf(__int_as_float(e7.y), (float)v7[0], ax1); ay1 = fmaf(__int_as_float(e7.y), (float)v7[1], ay1);
  }
  for (; p < pend; ++p){
    int2 e = csr_sw[p];
    float w = __int_as_float(e.y);
    f16x2 v = *(const f16x2*)(hb + (size_t)e.x*128);
    ax0 = fmaf(w, (float)v[0], ax0); ay0 = fmaf(w, (float)v[1], ay0);
  }
  float ax = ax0 + ax1, ay = ay0 + ay1;
  ushort_t hx, lx, hy, ly;
  split2(ax, hx, lx);
  split2(ay, hy, ly);
  size_t o = (size_t)node*128 + lane*2;
  ohi[o] = hx; ohi[o+1] = hy;
  olo[o] = lx; olo[o+1] = ly;
}

// ---------------- BatchNorm ----------------
__global__ void zero_stats(float* __restrict__ stats){
  stats[threadIdx.x] = 0.f;   // 512 threads
}

__global__ __launch_bounds__(256) void bn_partial(const float* __restrict__ a,
                                                  float* __restrict__ stats, int n){
  int c = threadIdx.x;
  int r0 = blockIdx.x * 256;
  int rend = min(r0 + 256, n);
  float s = 0.f, s2 = 0.f;
  for (int r = r0; r < rend; ++r){
    float v = a[(size_t)r*256 + c];
    s += v;
    s2 = fmaf(v, v, s2);
  }
  atomicAdd(&stats[c], s);
  atomicAdd(&stats[256 + c], s2);
}

__global__ void bn_final(float* __restrict__ stats, const float* __restrict__ g,
                         const float* __restrict__ be, int n){
  int c = threadIdx.x;
  float inv_n = 1.0f / (float)n;
  float mean = stats[c] * inv_n;
  float var  = fmaxf(stats[256 + c] * inv_n - mean*mean, 0.f);
  float sc   = g[c] * rsqrtf(var + EPS_BN);
  stats[512 + c] = sc;
  stats[768 + c] = be[c] - mean * sc;
}

// bn scale/shift + leaky, emit hi/lo bf16 split directly (feeds next MFMA GEMM)
__global__ __launch_bounds__(256) void bn_apply_split(const float* __restrict__ a,
    const float* __restrict__ stats, ushort_t* __restrict__ hi, ushort_t* __restrict__ lo, int n){
  size_t i = (size_t)blockIdx.x*256 + threadIdx.x;   // one float4 per thread
  if (i >= (size_t)n*64) return;
  int c4 = (int)(i & 63);
  float4 v  = ((const float4*)a)[i];
  float4 sc = ((const float4*)(stats + 512))[c4];
  float4 sh = ((const float4*)(stats + 768))[c4];
  v.x = lk(fmaf(v.x, sc.x, sh.x));
  v.y = lk(fmaf(v.y, sc.y, sh.y));
  v.z = lk(fmaf(v.z, sc.z, sh.z));
  v.w = lk(fmaf(v.w, sc.w, sh.w));
  ushort4 h, l;
  split2(v.x, h.x, l.x); split2(v.y, h.y, l.y);
  split2(v.z, h.z, l.z); split2(v.w, h.w, l.w);
  ((ushort4*)hi)[i] = h;
  ((ushort4*)lo)[i] = l;
}

// W[K][M] fp32 -> transposed split WtHi/WtLo[M][K] bf16
__global__ void wsplit(const float* __restrict__ W, ushort_t* __restrict__ hiT,
                       ushort_t* __restrict__ loT, int K, int M){
  int i = blockIdx.x*256 + threadIdx.x;
  if (i >= K*M) return;
  int k = i / M, m = i % M;
  ushort_t h, l;
  split2(W[i], h, l);
  hiT[(size_t)m*K + k] = h;
  loT[(size_t)m*K + k] = l;
}

// ---------------- bf16x3 split MFMA GEMM ----------------
// C[n,M] = (Ahi+Alo)[n,K] @ (Bhi+Blo)^T  with B stored transposed [M][K].
// ACT: 0 none ; 1 bias+leaky ; 2 bias.
// OMODE: 0 fp32->Cf ; 1 split bf16->Chi/Clo ; 2 fp16->Ch
template<int BM, int BN, int WM, int WN, int ACT, int OMODE>
__global__ __launch_bounds__(256) void gemm_mfma(
    const ushort_t* __restrict__ Ahi_g, const ushort_t* __restrict__ Alo_g,
    const ushort_t* __restrict__ Bhi_g, const ushort_t* __restrict__ Blo_g,
    const float* __restrict__ bias,
    float* __restrict__ Cf, ushort_t* __restrict__ Chi, ushort_t* __restrict__ Clo,
    f16* __restrict__ Ch,
    int nrows, int K, int M){
  constexpr int FI = WM/16, FJ = WN/16;
  constexpr int WCOLS = BN/WN;
  __shared__ ushort_t sAhi[BM*32];
  __shared__ ushort_t sAlo[BM*32];
  __shared__ ushort_t sBhi[BN*32];
  __shared__ ushort_t sBlo[BN*32];
  const int tid  = threadIdx.x;
  const int wave = tid >> 6;
  const int lane = tid & 63;
  const int r0 = blockIdx.x * BM;
  const int c0 = blockIdx.y * BN;
  const int wr0 = (wave / WCOLS) * WM;
  const int wc0 = (wave % WCOLS) * WN;
  const int m = lane & 15, q = lane >> 4;

  v4f acc[FI][FJ];
#pragma unroll
  for (int i = 0; i < FI; ++i)
#pragma unroll
    for (int j = 0; j < FJ; ++j) acc[i][j] = (v4f){0.f,0.f,0.f,0.f};

  const int srow = lane >> 2;                        // row within 16-row chunk
  const int kqlog = (lane & 3) ^ ((srow >> 1) & 3);  // swizzled logical 16B chunk
  const int fsw = (q ^ ((m >> 1) & 3)) * 8;          // frag read: swizzled k elem offset

  for (int kt = 0; kt < K; kt += 32){
#pragma unroll
    for (int c = 0; c < BM/64; ++c){                 // each wave stages BM/64 16-row A-chunks
      int cc = c*4 + wave;
      int gr = r0 + cc*16 + srow;
      gr = min(gr, nrows - 1);
      size_t go = (size_t)gr*K + kt + kqlog*8;
      gload16(Ahi_g + go, &sAhi[cc*512]);
      gload16(Alo_g + go, &sAlo[cc*512]);
    }
    for (int cc = wave; cc < BN/16; cc += 4){
      int gr = c0 + cc*16 + srow;
      size_t go = (size_t)gr*K + kt + kqlog*8;
      gload16(Bhi_g + go, &sBhi[cc*512]);
      gload16(Blo_g + go, &sBlo[cc*512]);
    }
    __syncthreads();   // drains vmcnt (global_load_lds) per barrier semantics

    v8s ah[FI], al[FI], bh[FJ], bl[FJ];
#pragma unroll
    for (int i = 0; i < FI; ++i){
      int off = (wr0 + i*16 + m)*32 + fsw;
      ah[i] = *(const v8s*)&sAhi[off];
      al[i] = *(const v8s*)&sAlo[off];
    }
#pragma unroll
    for (int j = 0; j < FJ; ++j){
      int off = (wc0 + j*16 + m)*32 + fsw;
      bh[j] = *(const v8s*)&sBhi[off];
      bl[j] = *(const v8s*)&sBlo[off];
    }
#pragma unroll
    for (int i = 0; i < FI; ++i)
#pragma unroll
      for (int j = 0; j < FJ; ++j){
        acc[i][j] = __builtin_amdgcn_mfma_f32_16x16x32_bf16(ah[i], bh[j], acc[i][j], 0, 0, 0);
        acc[i][j] = __builtin_amdgcn_mfma_f32_16x16x32_bf16(ah[i], bl[j], acc[i][j], 0, 0, 0);
        acc[i][j] = __builtin_amdgcn_mfma_f32_16x16x32_bf16(al[i], bh[j], acc[i][j], 0, 0, 0);
      }
    __syncthreads();
  }

  // epilogue: C/D layout col = lane&15, row = (lane>>4)*4 + reg  [m89/m91]
#pragma unroll
  for (int i = 0; i < FI; ++i){
#pragma unroll
    for (int j = 0; j < FJ; ++j){
      int col = c0 + wc0 + j*16 + m;
      float bv = (ACT >= 1) ? bias[col] : 0.f;
#pragma unroll
      for (int r = 0; r < 4; ++r){
        int row = r0 + wr0 + i*16 + q*4 + r;
        if (row >= nrows) continue;
        float v = acc[i][j][r] + bv;
        if (ACT == 1) v = lk(v);
        size_t o = (size_t)row*M + col;
        if (OMODE == 1){
          ushort_t h, l; split2(v, h, l);
          Chi[o] = h; Clo[o] = l;
        } else if (OMODE == 2){
          Ch[o] = (f16)v;
        } else {
          Cf[o] = v;
        }
      }
    }
  }
}

// ---------------- launch ----------------
extern "C" void kernel_launch(void* const* d_in, const int* in_sizes, int n_in,
                              void* d_out, int out_size, void* d_ws, size_t ws_size,
                              hipStream_t stream){
  const float* x   = (const float*)d_in[0];
  const int*   ei  = (const int*)  d_in[1];
  const float* ew  = (const float*)d_in[2];
  const float* W1  = (const float*)d_in[3];
  const float* b1  = (const float*)d_in[4];
  const float* g1  = (const float*)d_in[5];
  const float* be1 = (const float*)d_in[6];
  const float* W2  = (const float*)d_in[7];
  const float* b2  = (const float*)d_in[8];
  const float* g2  = (const float*)d_in[9];
  const float* be2 = (const float*)d_in[10];
  const float* W3  = (const float*)d_in[11];
  const float* b3  = (const float*)d_in[12];
  const float* g3  = (const float*)d_in[13];
  const float* be3 = (const float*)d_in[14];
  const float* Wl1 = (const float*)d_in[15];
  const float* bl1 = (const float*)d_in[16];
  const float* Wl2 = (const float*)d_in[17];
  const float* bl2 = (const float*)d_in[18];
  const int* src = ei;
  const int* dst = ei + NE;

  // ---- workspace: 2-slot rotation + in-slot aliases, total ~222 MB (proven) ----
  char* p = (char*)d_ws;
  auto carve = [&](size_t bytes)->void*{
    void* r = (void*)p;
    p += (bytes + 255) & ~(size_t)255;
    return r;
  };
  float*    dinv    = (float*)   carve((size_t)NN*4);
  int*      rp      = (int*)     carve((size_t)(NN+1)*4);
  int*      cnt     = (int*)     carve((size_t)NN*4);
  int*      bsum    = (int*)     carve(256*4);
  float*    stats   = (float*)   carve(1024*4);
  u64*      acc64   = (u64*)     carve((size_t)NN*8);
  int2*     csr_sw  = (int2*)    carve((size_t)NE*8);
  float*    S1      = (float*)   carve((size_t)NN*256*4);   // 102.4 MB slot
  float*    S2      = (float*)   carve((size_t)NN*256*4);   // 102.4 MB slot
  ushort_t* W1tH    = (ushort_t*)carve(128*256*2);
  ushort_t* W1tL    = (ushort_t*)carve(128*256*2);
  ushort_t* W2tH    = (ushort_t*)carve(256*256*2);
  ushort_t* W2tL    = (ushort_t*)carve(256*256*2);
  ushort_t* W3tH    = (ushort_t*)carve(256*256*2);
  ushort_t* W3tL    = (ushort_t*)carve(256*256*2);
  ushort_t* Wl1tH   = (ushort_t*)carve(256*256*2);
  ushort_t* Wl1tL   = (ushort_t*)carve(256*256*2);
  ushort_t* Wl2tH   = (ushort_t*)carve(256*32*2);
  ushort_t* Wl2tL   = (ushort_t*)carve(256*32*2);

  // aliased views (stream-order makes each safe):
  ushort_t* S1h256 = (ushort_t*)S1;  ushort_t* S1l256 = S1h256 + (size_t)NN*256;
  ushort_t* S2h256 = (ushort_t*)S2;  ushort_t* S2l256 = S2h256 + (size_t)NN*256;
  ushort_t* S1h128 = (ushort_t*)S1;  ushort_t* S1l128 = S1h128 + (size_t)NN*128;
  ushort_t* rank   = (ushort_t*)S2;       // 3.2 MB, consumed by fill_csr before cvt_x writes S2
  f16*      x16    = (f16*)S2;            // 25.6 MB, dead once spmm_x16 done
  f16*      H2f16  = (f16*)S2;            // conv2 gemm out, 51.2 MB, dead once spmm16 done
  f16*      H3f16  = (f16*)S1;            // conv3 gemm out, 51.2 MB, dead once spmm16 done

  const int nb = (NN + 1023) / 1024;
  const int spmm_blocks = (NN + 3) / 4;

  // graph preprocessing (shared by all 3 conv layers); rank aliases S2 and is
  // fully consumed by fill_csr_k BEFORE cvt_x overwrites S2.
  zero_acc<<<(NN+255)/256, 256, 0, stream>>>(acc64, NN);
  edge_hist<<<(NE+255)/256, 256, 0, stream>>>(dst, ew, acc64, rank, NE);
  finalize_acc<<<(NN+255)/256, 256, 0, stream>>>(acc64, dinv, cnt, NN);
  scan_block<<<nb, 1024, 0, stream>>>(cnt, rp, bsum, NN);
  scan_small<<<1, 128, 0, stream>>>(bsum, nb);
  scan_add<<<nb, 1024, 0, stream>>>(rp, bsum, NN, NE);
  fill_csr_k<<<(NE+255)/256, 256, 0, stream>>>(src, dst, ew, dinv, rp, rank, csr_sw, NE);

  // weight splits
  wsplit<<<(128*256+255)/256, 256, 0, stream>>>(W1,  W1tH,  W1tL,  128, 256);
  wsplit<<<(256*256+255)/256, 256, 0, stream>>>(W2,  W2tH,  W2tL,  256, 256);
  wsplit<<<(256*256+255)/256, 256, 0, stream>>>(W3,  W3tH,  W3tL,  256, 256);
  wsplit<<<(256*256+255)/256, 256, 0, stream>>>(Wl1, Wl1tH, Wl1tL, 256, 256);
  wsplit<<<(256*32 +255)/256, 256, 0, stream>>>(Wl2, Wl2tH, Wl2tL, 256, 32);

  dim3 gridBig((NN+127)/128, 2);
  dim3 gridOut((NN+127)/128, 1);

  auto run_bn = [&](const float* fin, ushort_t* hi, ushort_t* lo,
                    const float* g, const float* be){
    zero_stats<<<1, 512, 0, stream>>>(stats);
    bn_partial<<<(NN+255)/256, 256, 0, stream>>>(fin, stats, NN);
    bn_final<<<1, 256, 0, stream>>>(stats, g, be, NN);
    bn_apply_split<<<(int)(((size_t)NN*64 + 255)/256), 256, 0, stream>>>(fin, stats, hi, lo, NN);
  };

  // conv1 (aggregate-first): x->fp16 (x16 in S2, after rank is dead) ;
  // spmm gather fp16 -> bf16 split in S1 ; gemm+b1 -> S2 fp32 ; bn -> S1 split
  cvt_x<<<(NN*32+255)/256, 256, 0, stream>>>(x, x16, NN*32);
  spmm_x16<<<spmm_blocks, 256, 0, stream>>>(x16, rp, csr_sw, dinv, S1h128, S1l128, NN);
  gemm_mfma<128,128,64,64,2,0><<<gridBig, 256, 0, stream>>>(
      S1h128, S1l128, W1tH, W1tL, b1, S2, nullptr, nullptr, nullptr, NN, 128, 256);
  run_bn(S2, S1h256, S1l256, g1, be1);

  // conv2: gemm S1 split -> fp16 H in S2 ; spmm16 H -> S1 fp32 ; bn S1 -> S2 split
  gemm_mfma<128,128,64,64,0,2><<<gridBig, 256, 0, stream>>>(
      S1h256, S1l256, W2tH, W2tL, nullptr, nullptr, nullptr, nullptr, H2f16, NN, 256, 256);
  spmm16<<<spmm_blocks, 256, 0, stream>>>(H2f16, rp, csr_sw, dinv, b2, S1, NN);
  run_bn(S1, S2h256, S2l256, g2, be2);

  // conv3: gemm S2 split -> fp16 H in S1 ; spmm16 H -> S2 fp32 ; bn S2 -> S1 split
  gemm_mfma<128,128,64,64,0,2><<<gridBig, 256, 0, stream>>>(
      S2h256, S2l256, W3tH, W3tL, nullptr, nullptr, nullptr, nullptr, H3f16, NN, 256, 256);
  spmm16<<<spmm_blocks, 256, 0, stream>>>(H3f16, rp, csr_sw, dinv, b3, S2, NN);
  run_bn(S2, S1h256, S1l256, g3, be3);

  // head: leaky(h @ Wl1 + bl1) -> S2 split ; then @ Wl2 + bl2 -> d_out
  gemm_mfma<128,128,64,64,1,1><<<gridBig, 256, 0, stream>>>(
      S1h256, S1l256, Wl1tH, Wl1tL, bl1, nullptr, S2h256, S2l256, nullptr, NN, 256, 256);
  gemm_mfma<128,32,32,32,2,0><<<gridOut, 256, 0, stream>>>(
      S2h256, S2l256, Wl2tH, Wl2tL, bl2, (float*)d_out, nullptr, nullptr, nullptr, NN, 256, 32);
}